// Round 13
// baseline (300.645 us; speedup 1.0000x reference)
//
#include <hip/hip_runtime.h>
#include <hip/hip_bf16.h>
#include <math.h>
#include <stdint.h>

// ---------------------------------------------------------------------------
// GPT-2 self-attention forward, MI355X (gfx950).
// Pipeline: cvt3(fp32->bf16) -> GEMM1(qkv, fused bias+scatter)
//           -> flash attention (causal, max-free exp2, QBLK=128, dbuf KV)
//           -> GEMM2(proj, fused bias, fp32 out)
// B=4, T=2048, C=1024, H=16, D=64.
// r12 measured: attn 103.6us @ MfmaUtil 15.4 / VALUBusy 38.6 / Occ 21% ->
// latency-bound (both pipes idle). This round: 2 q-strips per staged KV tile
// (halves staging+barrier+vmcnt-drain per unit work) + 4 blocks/CU.
// Workspace: yb aliases xb -> 72MB.
// ---------------------------------------------------------------------------

typedef __attribute__((ext_vector_type(8))) short bf16x8;  // 8 bf16 = 4 VGPRs
typedef __attribute__((ext_vector_type(4))) float f32x4;

#define MFMA16(a, b, c) __builtin_amdgcn_mfma_f32_16x16x32_bf16((a), (b), (c), 0, 0, 0)

#define GLOAD_LDS16(gptr, lptr)                                                        \
  __builtin_amdgcn_global_load_lds((const __attribute__((address_space(1))) void*)(gptr), \
                                   (__attribute__((address_space(3))) void*)(lptr), 16, 0, 0)

__device__ __forceinline__ short f2bf(float f) {
  uint32_t u = __builtin_bit_cast(uint32_t, f);
  u = (u + 0x7FFFu + ((u >> 16) & 1u)) >> 16;  // RNE, finite inputs
  return (short)u;
}

// pack 2 f32 -> 2 bf16 (RNE) in one instr; lo=a, hi=b
__device__ __forceinline__ uint32_t cvtpk_bf16(float a, float b) {
  uint32_t pk;
  asm("v_cvt_pk_bf16_f32 %0, %1, %2" : "=v"(pk) : "v"(a), "v"(b));
  return pk;
}

// ------------------- fp32 -> bf16 convert (3 regions, 1 launch) ------------
__global__ void cvt3_f32_bf16(const float* __restrict__ x, short* __restrict__ ox, int nx4,
                              const float* __restrict__ wa, short* __restrict__ owa, int nwa4,
                              const float* __restrict__ wp, short* __restrict__ owp, int nwp4) {
  int i = blockIdx.x * 256 + threadIdx.x;
  const float* src;
  short* dst;
  int j;
  if (i < nx4) {
    src = x; dst = ox; j = i;
  } else if (i < nx4 + nwa4) {
    src = wa; dst = owa; j = i - nx4;
  } else if (i < nx4 + nwa4 + nwp4) {
    src = wp; dst = owp; j = i - nx4 - nwa4;
  } else {
    return;
  }
  float4 v = ((const float4*)src)[j];
  short4 o;
  o.x = f2bf(v.x); o.y = f2bf(v.y); o.z = f2bf(v.z); o.w = f2bf(v.w);
  ((short4*)dst)[j] = o;
}

// ---------------------------- GEMM: C = A * B^T ----------------------------
// (unchanged from r12 — m97 structure, 128x128 tile, BK=32)
template <int MODE>
__global__ __launch_bounds__(256, 3)
void gemm_bt(const short* __restrict__ A, const short* __restrict__ B,
             const float* __restrict__ bias, int K, int N,
             short* __restrict__ q, short* __restrict__ kk,
             short* __restrict__ vt, float* __restrict__ out) {
  __shared__ short As[128 * 32];
  __shared__ short Bs[128 * 32];
  const int tid = threadIdx.x;
  const int lane = tid & 63;
  const int w = tid >> 6;
  const int wm = w >> 1, wn = w & 1;
  const int bn = blockIdx.x, bm = blockIdx.y;
  const char* Ab = (const char*)A + (size_t)bm * 128 * K * 2;
  const char* Bb = (const char*)B + (size_t)bn * 128 * K * 2;
  const int rstride = K * 2;  // row stride bytes

  f32x4 acc[4][4] = {};

  for (int k0 = 0; k0 < K; k0 += 32) {
#pragma unroll
    for (int i = 0; i < 2; ++i) {
      const int off = i * 4096 + w * 1024 + lane * 16;
      const int row = off >> 6, cb = off & 63;
      GLOAD_LDS16(Ab + (size_t)row * rstride + k0 * 2 + cb, (char*)As + off);
      GLOAD_LDS16(Bb + (size_t)row * rstride + k0 * 2 + cb, (char*)Bs + off);
    }
    __syncthreads();

    bf16x8 a[4], b[4];
#pragma unroll
    for (int mi = 0; mi < 4; ++mi)
      a[mi] = *(const bf16x8*)&As[(wm * 64 + mi * 16 + (lane & 15)) * 32 + (lane >> 4) * 8];
#pragma unroll
    for (int ni = 0; ni < 4; ++ni)
      b[ni] = *(const bf16x8*)&Bs[(wn * 64 + ni * 16 + (lane & 15)) * 32 + (lane >> 4) * 8];
#pragma unroll
    for (int mi = 0; mi < 4; ++mi)
#pragma unroll
      for (int ni = 0; ni < 4; ++ni)
        acc[mi][ni] = MFMA16(a[mi], b[ni], acc[mi][ni]);
    __syncthreads();
  }

  // epilogue. C/D layout: col = lane&15, row = (lane>>4)*4 + r  [m89/m91]
  if (MODE == 0) {
    const int part = bn >> 3;  // 0=Q 1=K 2=V
    if (part == 2) {
      const int bb = bm >> 4;
#pragma unroll
      for (int mi = 0; mi < 4; ++mi) {
        const int t0 = (bm & 15) * 128 + wm * 64 + mi * 16 + (lane >> 4) * 4;
#pragma unroll
        for (int ni = 0; ni < 4; ++ni) {
          const int c = bn * 128 + wn * 64 + ni * 16 + (lane & 15) - 2048;
          const int h = c >> 6, d = c & 63;
          const float bv = bias[c + 2048];
          uint2 pk;
          pk.x = cvtpk_bf16(acc[mi][ni][0] + bv, acc[mi][ni][1] + bv);
          pk.y = cvtpk_bf16(acc[mi][ni][2] + bv, acc[mi][ni][3] + bv);
          *(uint2*)&vt[(((size_t)bb * 16 + h) * 64 + d) * 2048 + t0] = pk;
        }
      }
    } else {
      short* dst = (part == 0) ? q : kk;
      const float sc = (part == 0) ? 0.125f * 1.44269504f : 1.0f;
#pragma unroll
      for (int mi = 0; mi < 4; ++mi) {
#pragma unroll
        for (int ni = 0; ni < 4; ++ni) {
          const int n = bn * 128 + wn * 64 + ni * 16 + (lane & 15);
          const int c = n & 1023, h = c >> 6, d = c & 63;
          const float bv = bias[n];
#pragma unroll
          for (int r = 0; r < 4; ++r) {
            const int m = bm * 128 + wm * 64 + mi * 16 + (lane >> 4) * 4 + r;
            const int bb = m >> 11, t = m & 2047;
            dst[(((size_t)bb * 16 + h) * 2048 + t) * 64 + d] =
                f2bf((acc[mi][ni][r] + bv) * sc);
          }
        }
      }
    }
  } else {
#pragma unroll
    for (int mi = 0; mi < 4; ++mi)
#pragma unroll
      for (int ni = 0; ni < 4; ++ni) {
        const int n = bn * 128 + wn * 64 + ni * 16 + (lane & 15);
        const float bv = bias[n];
#pragma unroll
        for (int r = 0; r < 4; ++r) {
          const int m = bm * 128 + wm * 64 + mi * 16 + (lane >> 4) * 4 + r;
          out[(size_t)m * N + n] = acc[mi][ni][r] + bv;
        }
      }
  }
}

// ------------------------------ flash attention ----------------------------
// 1D grid of 1024 blocks (QBLK=128: 2 q-strips of 64), 256 thr = 4 waves.
// XCD swizzle: swz=(o&7)*128+o/8 (bijective, 1024%8==0); heavy-first qb.
// Each staged KV tile serves BOTH strips -> staging/barrier cost per unit
// work halved vs r12. Strip s diagonal at kt==2qb+s; strip0 skips kt=2qb+1
// (fully masked, block-uniform). Max-free exp2 softmax; l via MFMA ones-col;
// P via cvt_pk -> LDS (swizzled, same-wave reuse across strips).
// LDS 40KB -> 4 blocks/CU with (256,4).
__global__ __launch_bounds__(256, 4)
void attn64(const short* __restrict__ Q, const short* __restrict__ Kd,
            const short* __restrict__ Vt, short* __restrict__ Y) {
  const int o = blockIdx.x;                   // 0..1023
  const int swz = (o & 7) * 128 + (o >> 3);   // XCD-contiguous chunks
  const int bh = swz >> 4;                    // b*16 + h, 0..63
  const int qb = 15 - (swz & 15);             // q block (128 rows), heavy-first
  const int tid = threadIdx.x, lane = tid & 63, w = tid >> 6;

  __shared__ short Ks[2][64 * 64];   // [buf][kv_t][d]
  __shared__ short Vs[2][64 * 64];   // [buf][d][kv_t]
  __shared__ short Ps[4][16 * 64];   // per-wave P tile [q][kv_t]; O at end

  const char* qg = (const char*)(Q + (size_t)bh * 2048 * 64);
  const char* kg = (const char*)(Kd + (size_t)bh * 2048 * 64);
  const char* vg = (const char*)(Vt + (size_t)bh * 64 * 2048);

  // Q fragments per strip (A operand: row = lane&15, k = (lane>>4)*8+j)
  bf16x8 qa[2][2];
#pragma unroll
  for (int s = 0; s < 2; ++s) {
    const int qrowA = qb * 128 + s * 64 + w * 16 + (lane & 15);
#pragma unroll
    for (int dc = 0; dc < 2; ++dc)
      qa[s][dc] = *(const bf16x8*)(qg + (size_t)qrowA * 128 + dc * 64 + (lane >> 4) * 16);
  }

  // ones-column B fragment: B[n][k] = 1.0 iff n==0 (n = lane&15)
  bf16x8 bones;
  {
    const short v = ((lane & 15) == 0) ? (short)0x3F80 : (short)0;
#pragma unroll
    for (int j = 0; j < 8; ++j) bones[j] = v;
  }

  auto stage = [&](int buf, int kt) {
#pragma unroll
    for (int i = 0; i < 2; ++i) {
      const int off = i * 4096 + w * 1024 + lane * 16;
      const int row = off >> 7, cb = off & 127;  // 128B rows
      const int scb = cb ^ ((row & 7) << 4);     // inverse-swizzled source
      GLOAD_LDS16(kg + (size_t)(kt * 64 + row) * 128 + scb, (char*)Ks[buf] + off);
      GLOAD_LDS16(vg + (size_t)row * 4096 + kt * 128 + scb, (char*)Vs[buf] + off);
    }
  };

  f32x4 oacc[2][4] = {};
  f32x4 lacc[2] = {};
  const int ktmax = 2 * qb + 1;

  stage(0, 0);
  __syncthreads();
  int cur = 0;

  for (int kt = 0; kt <= ktmax; ++kt) {
    if (kt < ktmax) stage(cur ^ 1, kt + 1);

    const char* ks = (const char*)Ks[cur];
    const char* vs = (const char*)Vs[cur];
    char* pw = (char*)&Ps[w][0];

#pragma unroll
    for (int s = 0; s < 2; ++s) {
      if (s == 0 && kt == ktmax) continue;  // strip0 fully masked at last tile

      // S = Q K^T : 16q x 64k, 8 MFMA (log2 domain via Q pre-scale)
      f32x4 sacc[4] = {};
      __builtin_amdgcn_s_setprio(1);
#pragma unroll
      for (int dc = 0; dc < 2; ++dc) {
#pragma unroll
        for (int ni = 0; ni < 4; ++ni) {
          const int row = ni * 16 + (lane & 15);
          const int bo = (dc * 64 + (lane >> 4) * 16) ^ ((row & 7) << 4);
          bf16x8 kf = *(const bf16x8*)(ks + row * 128 + bo);
          sacc[ni] = MFMA16(qa[s][dc], kf, sacc[ni]);
        }
      }
      __builtin_amdgcn_s_setprio(0);

      if (kt == 2 * qb + s) {  // this strip's diagonal tile
        const int qrowD = qb * 128 + s * 64 + w * 16 + (lane >> 4) * 4;
#pragma unroll
        for (int ni = 0; ni < 4; ++ni) {
          const int col = kt * 64 + ni * 16 + (lane & 15);
#pragma unroll
          for (int r = 0; r < 4; ++r)
            if (col > qrowD + r) sacc[ni][r] = -INFINITY;
        }
      }

      // max-free P = exp2(S)
#pragma unroll
      for (int r = 0; r < 4; ++r)
#pragma unroll
        for (int ni = 0; ni < 4; ++ni)
          sacc[ni][r] = exp2f(sacc[ni][r]);

      // P -> per-wave LDS (bf16 via cvt_pk, swizzled)
#pragma unroll
      for (int r = 0; r < 4; ++r) {
        const int prow = (lane >> 4) * 4 + r;
        const int rowoff = prow * 128;
        const int sw = (prow & 7) << 4;
#pragma unroll
        for (int ni = 0; ni < 4; ni += 2) {
          const uint32_t pk = cvtpk_bf16(sacc[ni][r], sacc[ni + 1][r]);
          const int a0 = rowoff + ((((ni) * 16 + (lane & 15)) * 2) ^ sw);
          const int a1 = rowoff + ((((ni + 1) * 16 + (lane & 15)) * 2) ^ sw);
          *(short*)(pw + a0) = (short)(pk & 0xFFFFu);
          *(short*)(pw + a1) = (short)(pk >> 16);
        }
      }
      asm volatile("s_waitcnt lgkmcnt(0)" ::: "memory");  // same-wave RAW on Ps

      bf16x8 pa[2];
#pragma unroll
      for (int kc = 0; kc < 2; ++kc) {
        const int prow = lane & 15;
        const int pbo = (kc * 64 + (lane >> 4) * 16) ^ ((prow & 7) << 4);
        pa[kc] = *(const bf16x8*)(pw + prow * 128 + pbo);
      }

      // O += P V ; l += P * ones (MFMA pipe does the row-sum)
      __builtin_amdgcn_s_setprio(1);
#pragma unroll
      for (int nd = 0; nd < 4; ++nd)
#pragma unroll
        for (int kc = 0; kc < 2; ++kc) {
          const int row = nd * 16 + (lane & 15);
          const int bo = (kc * 64 + (lane >> 4) * 16) ^ ((row & 7) << 4);
          bf16x8 vf = *(const bf16x8*)(vs + row * 128 + bo);
          oacc[s][nd] = MFMA16(pa[kc], vf, oacc[s][nd]);
        }
      lacc[s] = MFMA16(pa[0], bones, lacc[s]);
      lacc[s] = MFMA16(pa[1], bones, lacc[s]);
      __builtin_amdgcn_s_setprio(0);
    }

    __syncthreads();  // buf[cur] reads done; prefetch into buf[cur^1] landed
    cur ^= 1;
  }

  // ---- epilogue per strip: O -> Ps[w] (bf16, swizzled) -> 2x16B stores ----
  const int b = bh >> 4, h = bh & 15;
  char* pw = (char*)&Ps[w][0];
  const int qloc0 = (lane >> 4) * 4;
#pragma unroll
  for (int s = 0; s < 2; ++s) {
    float linv[4];
#pragma unroll
    for (int r = 0; r < 4; ++r) {
      const float l = __shfl(lacc[s][r], lane & 48);
      linv[r] = 1.0f / l;
    }
#pragma unroll
    for (int nd = 0; nd < 4; ++nd)
#pragma unroll
      for (int r = 0; r < 4; ++r) {
        const int row = qloc0 + r;
        const int bo = (nd * 32 + (lane & 15) * 2) ^ ((row & 7) << 4);
        *(short*)(pw + row * 128 + bo) = f2bf(oacc[s][nd][r] * linv[r]);
      }
    asm volatile("s_waitcnt lgkmcnt(0)" ::: "memory");  // same-wave RAW on Ps

#pragma unroll
    for (int half = 0; half < 2; ++half) {
      const int qlocal = half * 8 + (lane >> 3);      // 0..15
      const int dstart = (lane & 7) * 8;              // 0..56, 16B chunks
      const int bo = (dstart * 2) ^ ((qlocal & 7) << 4);
      bf16x8 v = *(const bf16x8*)(pw + qlocal * 128 + bo);
      const int t = qb * 128 + s * 64 + w * 16 + qlocal;
      *(bf16x8*)&Y[((size_t)b * 2048 + t) * 1024 + h * 64 + dstart] = v;
    }
    asm volatile("s_waitcnt lgkmcnt(0)" ::: "memory");  // reads done before s1 writes
  }
}

// ------------------------------- launcher ----------------------------------
extern "C" void kernel_launch(void* const* d_in, const int* in_sizes, int n_in,
                              void* d_out, int out_size, void* d_ws, size_t ws_size,
                              hipStream_t stream) {
  const float* x = (const float*)d_in[0];
  const float* w_attn = (const float*)d_in[1];
  const float* b_attn = (const float*)d_in[2];
  const float* w_proj = (const float*)d_in[3];
  const float* b_proj = (const float*)d_in[4];
  float* out = (float*)d_out;

  char* ws = (char*)d_ws;
  size_t o = 0;
  const size_t SZ = (size_t)8192 * 1024 * 2;  // 16 MB per [8192,1024] bf16
  short* xb = (short*)(ws + o);  o += SZ;     // bf16 x; DEAD after GEMM1
  short* wab = (short*)(ws + o); o += (size_t)3072 * 1024 * 2;
  short* wpb = (short*)(ws + o); o += (size_t)1024 * 1024 * 2;
  short* qw = (short*)(ws + o);  o += SZ;  // [b,h][t][d], log2e/8-scaled
  short* kw = (short*)(ws + o);  o += SZ;  // [b,h][t][d]
  short* vtw = (short*)(ws + o); o += SZ;  // [b,h][d][t]
  short* yb = xb;  // alias: attn writes yb strictly after GEMM1's last xb read

  cvt3_f32_bf16<<<12288, 256, 0, stream>>>(x, xb, 2097152,
                                           w_attn, wab, 786432,
                                           w_proj, wpb, 262144);

  gemm_bt<0><<<dim3(24, 64), 256, 0, stream>>>(xb, wab, b_attn, 1024, 3072,
                                               qw, kw, vtw, nullptr);
  attn64<<<1024, 256, 0, stream>>>(qw, kw, vtw, yb);
  gemm_bt<1><<<dim3(8, 64), 256, 0, stream>>>(yb, wpb, b_proj, 1024, 1024,
                                              nullptr, nullptr, nullptr, out);
}

// Round 14
// 292.349 us; speedup vs baseline: 1.0284x; 1.0284x over previous
//
#include <hip/hip_runtime.h>
#include <hip/hip_bf16.h>
#include <math.h>
#include <stdint.h>

// ---------------------------------------------------------------------------
// GPT-2 self-attention forward, MI355X (gfx950).
// Pipeline: cvt3(fp32->bf16) -> GEMM1(qkv, fused bias+scatter)
//           -> flash attention (causal, max-free exp2, 8-wave/128q blocks)
//           -> GEMM2(proj, fused bias, fp32 out)
// B=4, T=2048, C=1024, H=16, D=64.
// r12: attn 103.6us (256thr, 64q/block). r13 (2 serial strips, half the
// waves): REGRESSED to 118.6. This round: 512thr / 8 waves / 128q per block
// -> same amortization as r13 but strips run in PARALLEL, wave count back to
// r12's 8192, LDS 48KB -> 3 blocks/CU (24-wave cap vs 16).
// ---------------------------------------------------------------------------

typedef __attribute__((ext_vector_type(8))) short bf16x8;  // 8 bf16 = 4 VGPRs
typedef __attribute__((ext_vector_type(4))) float f32x4;

#define MFMA16(a, b, c) __builtin_amdgcn_mfma_f32_16x16x32_bf16((a), (b), (c), 0, 0, 0)

#define GLOAD_LDS16(gptr, lptr)                                                        \
  __builtin_amdgcn_global_load_lds((const __attribute__((address_space(1))) void*)(gptr), \
                                   (__attribute__((address_space(3))) void*)(lptr), 16, 0, 0)

__device__ __forceinline__ short f2bf(float f) {
  uint32_t u = __builtin_bit_cast(uint32_t, f);
  u = (u + 0x7FFFu + ((u >> 16) & 1u)) >> 16;  // RNE, finite inputs
  return (short)u;
}

// pack 2 f32 -> 2 bf16 (RNE) in one instr; lo=a, hi=b
__device__ __forceinline__ uint32_t cvtpk_bf16(float a, float b) {
  uint32_t pk;
  asm("v_cvt_pk_bf16_f32 %0, %1, %2" : "=v"(pk) : "v"(a), "v"(b));
  return pk;
}

// ------------------- fp32 -> bf16 convert (3 regions, 1 launch) ------------
__global__ void cvt3_f32_bf16(const float* __restrict__ x, short* __restrict__ ox, int nx4,
                              const float* __restrict__ wa, short* __restrict__ owa, int nwa4,
                              const float* __restrict__ wp, short* __restrict__ owp, int nwp4) {
  int i = blockIdx.x * 256 + threadIdx.x;
  const float* src;
  short* dst;
  int j;
  if (i < nx4) {
    src = x; dst = ox; j = i;
  } else if (i < nx4 + nwa4) {
    src = wa; dst = owa; j = i - nx4;
  } else if (i < nx4 + nwa4 + nwp4) {
    src = wp; dst = owp; j = i - nx4 - nwa4;
  } else {
    return;
  }
  float4 v = ((const float4*)src)[j];
  short4 o;
  o.x = f2bf(v.x); o.y = f2bf(v.y); o.z = f2bf(v.z); o.w = f2bf(v.w);
  ((short4*)dst)[j] = o;
}

// ---------------------------- GEMM: C = A * B^T ----------------------------
// (r12-measured state — m97 structure, 128x128 tile, BK=32; untouched)
template <int MODE>
__global__ __launch_bounds__(256, 3)
void gemm_bt(const short* __restrict__ A, const short* __restrict__ B,
             const float* __restrict__ bias, int K, int N,
             short* __restrict__ q, short* __restrict__ kk,
             short* __restrict__ vt, float* __restrict__ out) {
  __shared__ short As[128 * 32];
  __shared__ short Bs[128 * 32];
  const int tid = threadIdx.x;
  const int lane = tid & 63;
  const int w = tid >> 6;
  const int wm = w >> 1, wn = w & 1;
  const int bn = blockIdx.x, bm = blockIdx.y;
  const char* Ab = (const char*)A + (size_t)bm * 128 * K * 2;
  const char* Bb = (const char*)B + (size_t)bn * 128 * K * 2;
  const int rstride = K * 2;  // row stride bytes

  f32x4 acc[4][4] = {};

  for (int k0 = 0; k0 < K; k0 += 32) {
#pragma unroll
    for (int i = 0; i < 2; ++i) {
      const int off = i * 4096 + w * 1024 + lane * 16;
      const int row = off >> 6, cb = off & 63;
      GLOAD_LDS16(Ab + (size_t)row * rstride + k0 * 2 + cb, (char*)As + off);
      GLOAD_LDS16(Bb + (size_t)row * rstride + k0 * 2 + cb, (char*)Bs + off);
    }
    __syncthreads();

    bf16x8 a[4], b[4];
#pragma unroll
    for (int mi = 0; mi < 4; ++mi)
      a[mi] = *(const bf16x8*)&As[(wm * 64 + mi * 16 + (lane & 15)) * 32 + (lane >> 4) * 8];
#pragma unroll
    for (int ni = 0; ni < 4; ++ni)
      b[ni] = *(const bf16x8*)&Bs[(wn * 64 + ni * 16 + (lane & 15)) * 32 + (lane >> 4) * 8];
#pragma unroll
    for (int mi = 0; mi < 4; ++mi)
#pragma unroll
      for (int ni = 0; ni < 4; ++ni)
        acc[mi][ni] = MFMA16(a[mi], b[ni], acc[mi][ni]);
    __syncthreads();
  }

  // epilogue. C/D layout: col = lane&15, row = (lane>>4)*4 + r  [m89/m91]
  if (MODE == 0) {
    const int part = bn >> 3;  // 0=Q 1=K 2=V
    if (part == 2) {
      const int bb = bm >> 4;
#pragma unroll
      for (int mi = 0; mi < 4; ++mi) {
        const int t0 = (bm & 15) * 128 + wm * 64 + mi * 16 + (lane >> 4) * 4;
#pragma unroll
        for (int ni = 0; ni < 4; ++ni) {
          const int c = bn * 128 + wn * 64 + ni * 16 + (lane & 15) - 2048;
          const int h = c >> 6, d = c & 63;
          const float bv = bias[c + 2048];
          uint2 pk;
          pk.x = cvtpk_bf16(acc[mi][ni][0] + bv, acc[mi][ni][1] + bv);
          pk.y = cvtpk_bf16(acc[mi][ni][2] + bv, acc[mi][ni][3] + bv);
          *(uint2*)&vt[(((size_t)bb * 16 + h) * 64 + d) * 2048 + t0] = pk;
        }
      }
    } else {
      short* dst = (part == 0) ? q : kk;
      const float sc = (part == 0) ? 0.125f * 1.44269504f : 1.0f;
#pragma unroll
      for (int mi = 0; mi < 4; ++mi) {
#pragma unroll
        for (int ni = 0; ni < 4; ++ni) {
          const int n = bn * 128 + wn * 64 + ni * 16 + (lane & 15);
          const int c = n & 1023, h = c >> 6, d = c & 63;
          const float bv = bias[n];
#pragma unroll
          for (int r = 0; r < 4; ++r) {
            const int m = bm * 128 + wm * 64 + mi * 16 + (lane >> 4) * 4 + r;
            const int bb = m >> 11, t = m & 2047;
            dst[(((size_t)bb * 16 + h) * 2048 + t) * 64 + d] =
                f2bf((acc[mi][ni][r] + bv) * sc);
          }
        }
      }
    }
  } else {
#pragma unroll
    for (int mi = 0; mi < 4; ++mi)
#pragma unroll
      for (int ni = 0; ni < 4; ++ni) {
        const int n = bn * 128 + wn * 64 + ni * 16 + (lane & 15);
        const float bv = bias[n];
#pragma unroll
        for (int r = 0; r < 4; ++r) {
          const int m = bm * 128 + wm * 64 + mi * 16 + (lane >> 4) * 4 + r;
          out[(size_t)m * N + n] = acc[mi][ni][r] + bv;
        }
      }
  }
}

// ------------------------------ flash attention ----------------------------
// 1024 blocks x 512 thr (8 waves). Each block: 128 q-rows (wave w owns rows
// qb*128 + w*16 ..+15), one shared KV tile of 64 per barrier interval ->
// staging/barrier cost per unit work = half of r12, waves resident = 24/CU.
// XCD swizzle (o&7)*128+o/8 (bijective, 1024%8==0); heavy-first qb (LPT).
// Wave w diagonal tile = 2qb+(w>>2); waves 0-3 skip the (fully masked) last
// tile via wave-uniform guard (barrier still reached). Per-wave math is
// byte-identical to r12: max-free exp2 (log2-domain Q), l via MFMA ones-col,
// P via cvt_pk -> per-wave Ps (XOR-swizzled), coalesced 16B Y stores.
// LDS 48KB = 2x8KB K + 2x8KB V + 8x2KB Ps -> 3 blocks/CU.
__global__ __launch_bounds__(512, 3)
void attn64(const short* __restrict__ Q, const short* __restrict__ Kd,
            const short* __restrict__ Vt, short* __restrict__ Y) {
  const int o = blockIdx.x;                   // 0..1023
  const int swz = (o & 7) * 128 + (o >> 3);   // XCD-contiguous chunks
  const int bh = swz >> 4;                    // b*16 + h, 0..63
  const int qb = 15 - (swz & 15);             // q block (128 rows), heavy-first
  const int tid = threadIdx.x, lane = tid & 63, w = tid >> 6;  // w: 0..7

  __shared__ short Ks[2][64 * 64];   // [buf][kv_t][d]
  __shared__ short Vs[2][64 * 64];   // [buf][d][kv_t]
  __shared__ short Ps[8][16 * 64];   // per-wave P tile [q][kv_t]; O at end

  const char* qg = (const char*)(Q + (size_t)bh * 2048 * 64);
  const char* kg = (const char*)(Kd + (size_t)bh * 2048 * 64);
  const char* vg = (const char*)(Vt + (size_t)bh * 64 * 2048);

  // Q fragments (A operand: row = lane&15, k = (lane>>4)*8+j)
  bf16x8 qa[2];
  const int qrowA = qb * 128 + w * 16 + (lane & 15);
#pragma unroll
  for (int dc = 0; dc < 2; ++dc)
    qa[dc] = *(const bf16x8*)(qg + (size_t)qrowA * 128 + dc * 64 + (lane >> 4) * 16);

  // ones-column B fragment: B[n][k] = 1.0 iff n==0 (n = lane&15)
  bf16x8 bones;
  {
    const short v = ((lane & 15) == 0) ? (short)0x3F80 : (short)0;
#pragma unroll
    for (int j = 0; j < 8; ++j) bones[j] = v;
  }

  // stage K (8KB) + V^T (8KB): 512 threads x 16B each, 1 load per array.
  // LDS dest per wave = uniform base + lane*16 (required pattern).
  auto stage = [&](int buf, int kt) {
    const int off = tid * 16;                  // 0..8191
    const int row = off >> 7, cb = off & 127;  // 128B rows
    const int scb = cb ^ ((row & 7) << 4);     // inverse-swizzled source
    GLOAD_LDS16(kg + (size_t)(kt * 64 + row) * 128 + scb, (char*)Ks[buf] + off);
    GLOAD_LDS16(vg + (size_t)row * 4096 + kt * 128 + scb, (char*)Vs[buf] + off);
  };

  f32x4 oacc[4] = {};
  f32x4 lacc = {};  // col 0 = row sums of bf16 P (accumulated via MFMA)
  const int ktmax = 2 * qb + 1;
  const int dtile = 2 * qb + (w >> 2);  // this wave's diagonal tile

  stage(0, 0);
  __syncthreads();  // drains vmcnt(0): buf 0 ready
  int cur = 0;

  for (int kt = 0; kt <= ktmax; ++kt) {
    if (kt < ktmax) stage(cur ^ 1, kt + 1);  // prefetch next tile (overlapped)

    if (!(kt == ktmax && w < 4)) {  // waves 0-3 fully masked at last tile
      const char* ks = (const char*)Ks[cur];
      const char* vs = (const char*)Vs[cur];
      char* pw = (char*)&Ps[w][0];

      // S = Q K^T : 16q x 64k, 8 MFMA (log2 domain via Q pre-scale)
      f32x4 sacc[4] = {};
      __builtin_amdgcn_s_setprio(1);
#pragma unroll
      for (int dc = 0; dc < 2; ++dc) {
#pragma unroll
        for (int ni = 0; ni < 4; ++ni) {
          const int row = ni * 16 + (lane & 15);
          const int bo = (dc * 64 + (lane >> 4) * 16) ^ ((row & 7) << 4);
          bf16x8 kf = *(const bf16x8*)(ks + row * 128 + bo);
          sacc[ni] = MFMA16(qa[dc], kf, sacc[ni]);
        }
      }
      __builtin_amdgcn_s_setprio(0);

      if (kt == dtile) {  // diagonal tile: causal mask
        const int qrowD = qb * 128 + w * 16 + (lane >> 4) * 4;
#pragma unroll
        for (int ni = 0; ni < 4; ++ni) {
          const int col = kt * 64 + ni * 16 + (lane & 15);
#pragma unroll
          for (int r = 0; r < 4; ++r)
            if (col > qrowD + r) sacc[ni][r] = -INFINITY;
        }
      }

      // max-free P = exp2(S)  (exp2(-inf)=0 keeps the mask exact)
#pragma unroll
      for (int r = 0; r < 4; ++r)
#pragma unroll
        for (int ni = 0; ni < 4; ++ni)
          sacc[ni][r] = exp2f(sacc[ni][r]);

      // P -> per-wave LDS (bf16 via cvt_pk, swizzled)
#pragma unroll
      for (int r = 0; r < 4; ++r) {
        const int prow = (lane >> 4) * 4 + r;
        const int rowoff = prow * 128;
        const int sw = (prow & 7) << 4;
#pragma unroll
        for (int ni = 0; ni < 4; ni += 2) {
          const uint32_t pk = cvtpk_bf16(sacc[ni][r], sacc[ni + 1][r]);
          const int a0 = rowoff + ((((ni) * 16 + (lane & 15)) * 2) ^ sw);
          const int a1 = rowoff + ((((ni + 1) * 16 + (lane & 15)) * 2) ^ sw);
          *(short*)(pw + a0) = (short)(pk & 0xFFFFu);
          *(short*)(pw + a1) = (short)(pk >> 16);
        }
      }
      asm volatile("s_waitcnt lgkmcnt(0)" ::: "memory");  // same-wave RAW on Ps

      bf16x8 pa[2];
#pragma unroll
      for (int kc = 0; kc < 2; ++kc) {
        const int prow = lane & 15;
        const int pbo = (kc * 64 + (lane >> 4) * 16) ^ ((prow & 7) << 4);
        pa[kc] = *(const bf16x8*)(pw + prow * 128 + pbo);
      }

      // O += P V ; l += P * ones (MFMA pipe does the row-sum)
      __builtin_amdgcn_s_setprio(1);
#pragma unroll
      for (int nd = 0; nd < 4; ++nd)
#pragma unroll
        for (int kc = 0; kc < 2; ++kc) {
          const int row = nd * 16 + (lane & 15);
          const int bo = (kc * 64 + (lane >> 4) * 16) ^ ((row & 7) << 4);
          bf16x8 vf = *(const bf16x8*)(vs + row * 128 + bo);
          oacc[nd] = MFMA16(pa[kc], vf, oacc[nd]);
        }
      lacc = MFMA16(pa[0], bones, lacc);
      lacc = MFMA16(pa[1], bones, lacc);
      __builtin_amdgcn_s_setprio(0);
    }

    __syncthreads();  // buf[cur] reads done; prefetch into buf[cur^1] landed
    cur ^= 1;
  }

  // l for row q=(lane>>4)*4+r lives in col-0 lane of the 16-group: lane&48
  float linv[4];
#pragma unroll
  for (int r = 0; r < 4; ++r) {
    const float l = __shfl(lacc[r], lane & 48);
    linv[r] = 1.0f / l;
  }

  // ---- epilogue: stage O (bf16) into Ps[w] [16 q][64 d], swizzled rows ----
  // then 2 x 16B coalesced stores/lane (Y rows = 128B contiguous per head).
  char* pw = (char*)&Ps[w][0];
  const int qloc0 = (lane >> 4) * 4;
#pragma unroll
  for (int nd = 0; nd < 4; ++nd)
#pragma unroll
    for (int r = 0; r < 4; ++r) {
      const int row = qloc0 + r;
      const int bo = (nd * 32 + (lane & 15) * 2) ^ ((row & 7) << 4);
      *(short*)(pw + row * 128 + bo) = f2bf(oacc[nd][r] * linv[r]);
    }
  asm volatile("s_waitcnt lgkmcnt(0)" ::: "memory");  // same-wave RAW on Ps

  const int b = bh >> 4, h = bh & 15;
#pragma unroll
  for (int half = 0; half < 2; ++half) {
    const int qlocal = half * 8 + (lane >> 3);      // 0..15
    const int dstart = (lane & 7) * 8;              // 0..56, 16B chunks
    const int bo = (dstart * 2) ^ ((qlocal & 7) << 4);  // same involution
    bf16x8 v = *(const bf16x8*)(pw + qlocal * 128 + bo);
    const int t = qb * 128 + w * 16 + qlocal;
    *(bf16x8*)&Y[((size_t)b * 2048 + t) * 1024 + h * 64 + dstart] = v;
  }
}

// ------------------------------- launcher ----------------------------------
extern "C" void kernel_launch(void* const* d_in, const int* in_sizes, int n_in,
                              void* d_out, int out_size, void* d_ws, size_t ws_size,
                              hipStream_t stream) {
  const float* x = (const float*)d_in[0];
  const float* w_attn = (const float*)d_in[1];
  const float* b_attn = (const float*)d_in[2];
  const float* w_proj = (const float*)d_in[3];
  const float* b_proj = (const float*)d_in[4];
  float* out = (float*)d_out;

  char* ws = (char*)d_ws;
  size_t o = 0;
  const size_t SZ = (size_t)8192 * 1024 * 2;  // 16 MB per [8192,1024] bf16
  short* xb = (short*)(ws + o);  o += SZ;     // bf16 x; DEAD after GEMM1
  short* wab = (short*)(ws + o); o += (size_t)3072 * 1024 * 2;
  short* wpb = (short*)(ws + o); o += (size_t)1024 * 1024 * 2;
  short* qw = (short*)(ws + o);  o += SZ;  // [b,h][t][d], log2e/8-scaled
  short* kw = (short*)(ws + o);  o += SZ;  // [b,h][t][d]
  short* vtw = (short*)(ws + o); o += SZ;  // [b,h][d][t]
  short* yb = xb;  // alias: attn writes yb strictly after GEMM1's last xb read

  cvt3_f32_bf16<<<12288, 256, 0, stream>>>(x, xb, 2097152,
                                           w_attn, wab, 786432,
                                           w_proj, wpb, 262144);

  gemm_bt<0><<<dim3(24, 64), 256, 0, stream>>>(xb, wab, b_attn, 1024, 3072,
                                               qw, kw, vtw, nullptr);
  attn64<<<1024, 512, 0, stream>>>(qw, kw, vtw, yb);
  gemm_bt<1><<<dim3(8, 64), 256, 0, stream>>>(yb, wpb, b_proj, 1024, 1024,
                                              nullptr, nullptr, nullptr, out);
}